// Round 1
// baseline (439.503 us; speedup 1.0000x reference)
//
#include <hip/hip_runtime.h>

// Reverse (suffix) cumulative sum along dim=1 of a (2048, 32768) fp32 matrix.
// One block per row; row processed right-to-left in tiles of T*4 elements.
// Fully coalesced float4 loads/stores; hierarchical suffix scan per tile.

#define T 512               // threads per block (8 waves)
#define WAVES (T / 64)

__global__ __launch_bounds__(T) void rcumsum_rows(const float* __restrict__ x,
                                                  float* __restrict__ out,
                                                  int N) {
    __shared__ float warr[WAVES];

    const int row  = blockIdx.x;
    const long long rowbase = (long long)row * (long long)N;
    const float4* xin  = (const float4*)(x + rowbase);
    float4*       xout = (float4*)(out + rowbase);

    const int tid  = threadIdx.x;
    const int lane = tid & 63;
    const int wave = tid >> 6;

    const int nt4   = N >> 2;      // float4 slots per row (8192)
    const int tiles = nt4 / T;     // 16

    float carry = 0.0f;

    for (int tile = tiles - 1; tile >= 0; --tile) {
        // Coalesced vector load: lane t reads 16B at tile_base + 16*t.
        float4 v = xin[tile * T + tid];

        // Suffix sums within this thread's 4 consecutive elements.
        float l3 = v.w;
        float l2 = v.z + l3;
        float l1 = v.y + l2;
        float l0 = v.x + l1;       // = sum of all 4 (thread total)
        float s  = l0;

        // Wave-level inclusive suffix scan (Kogge-Stone over 64 lanes).
        float xs = s;
        #pragma unroll
        for (int d = 1; d < 64; d <<= 1) {
            float t = __shfl_down(xs, d);
            if (lane + d < 64) xs += t;
        }
        // lane 0 now holds the wave total (inclusive suffix from lane 0).
        if (lane == 0) warr[wave] = xs;
        __syncthreads();

        // Cross-wave: sum of totals of waves to the right, plus grand total.
        float waveoff = 0.0f, total = 0.0f;
        #pragma unroll
        for (int w = 0; w < WAVES; ++w) {
            float wv = warr[w];          // same address in all lanes: broadcast
            total += wv;
            if (w > wave) waveoff += wv;
        }

        // Exclusive suffix offset for this thread within the block + carry.
        float add = (xs - s) + waveoff + carry;
        carry += total;

        float4 o;
        o.x = l0 + add;
        o.y = l1 + add;
        o.z = l2 + add;
        o.w = l3 + add;
        xout[tile * T + tid] = o;

        __syncthreads();   // protect warr before next tile rewrites it
    }
}

extern "C" void kernel_launch(void* const* d_in, const int* in_sizes, int n_in,
                              void* d_out, int out_size, void* d_ws, size_t ws_size,
                              hipStream_t stream) {
    const float* x = (const float*)d_in[0];
    float* out = (float*)d_out;

    const int N = 32768;
    const int B = out_size / N;   // 2048

    rcumsum_rows<<<B, T, 0, stream>>>(x, out, N);
}

// Round 2
// 430.823 us; speedup vs baseline: 1.0201x; 1.0201x over previous
//
#include <hip/hip_runtime.h>

// Reverse (suffix) cumsum along dim=1 of (2048, 32768) fp32.
// One block per row. All 16 float4 loads per thread hoisted before a single
// barrier (16x MLP); hierarchical suffix scan entirely in registers + one
// LDS round-trip of 128 wave totals.

#define T 512               // threads per block (8 waves)
#define WAVES 8
#define TILES 16            // (32768/4) / 512

__global__ __launch_bounds__(T) void rcumsum_rows(const float* __restrict__ x,
                                                  float* __restrict__ out,
                                                  int N) {
    __shared__ float wtot[TILES][WAVES];   // per-(tile,wave) totals

    const int row = blockIdx.x;
    const long long rowbase = (long long)row * (long long)N;
    const float4* __restrict__ xin  = (const float4*)(x + rowbase);
    float4* __restrict__       xout = (float4*)(out + rowbase);

    const int tid  = threadIdx.x;
    const int lane = tid & 63;
    const int wave = tid >> 6;

    // Phase 1: issue ALL loads up front — 16 outstanding per thread.
    float4 v[TILES];
    #pragma unroll
    for (int t = 0; t < TILES; ++t) v[t] = xin[t * T + tid];

    // Phase 2: per-tile wave-level suffix scans (independent across tiles).
    // excl[t] = sum of group-sums of lanes > lane (exclusive suffix in wave).
    float excl[TILES];
    #pragma unroll
    for (int t = 0; t < TILES; ++t) {
        float g = v[t].x + v[t].y + v[t].z + v[t].w;   // this thread's group sum
        float acc = g;                                  // inclusive suffix scan
        #pragma unroll
        for (int d = 1; d < 64; d <<= 1) {
            float tmp = __shfl_down(acc, d);
            if (lane + d < 64) acc += tmp;
        }
        excl[t] = acc - g;
        if (lane == 0) wtot[t][wave] = acc;             // wave total
    }
    __syncthreads();   // the ONLY barrier

    // Phase 3: redundant carry computation from broadcast LDS reads + stores.
    float carry = 0.0f;
    #pragma unroll
    for (int t = TILES - 1; t >= 0; --t) {
        float tt = 0.0f, wo = 0.0f;
        #pragma unroll
        for (int w = 0; w < WAVES; ++w) {
            float val = wtot[t][w];      // same addr all lanes: broadcast, no conflict
            tt += val;
            if (w > wave) wo += val;
        }
        float add = excl[t] + wo + carry;

        float l3 = v[t].w;
        float l2 = v[t].z + l3;
        float l1 = v[t].y + l2;
        float l0 = v[t].x + l1;

        float4 o;
        o.x = l0 + add;
        o.y = l1 + add;
        o.z = l2 + add;
        o.w = l3 + add;
        xout[t * T + tid] = o;

        carry += tt;
    }
}

extern "C" void kernel_launch(void* const* d_in, const int* in_sizes, int n_in,
                              void* d_out, int out_size, void* d_ws, size_t ws_size,
                              hipStream_t stream) {
    const float* x = (const float*)d_in[0];
    float* out = (float*)d_out;

    const int N = 32768;
    const int B = out_size / N;   // 2048 rows

    rcumsum_rows<<<B, T, 0, stream>>>(x, out, N);
}